// Round 1
// baseline (656.851 us; speedup 1.0000x reference)
//
#include <hip/hip_runtime.h>
#include <math.h>

#define CDIV(a,b) (((a)+(b)-1)/(b))

// ---------------------------------------------------------------------------
// K1: in-degree histogram over dst
__global__ void k_hist(const int* __restrict__ dst, int* __restrict__ deg, int E) {
    int stride = gridDim.x * blockDim.x;
    for (int e = blockIdx.x * blockDim.x + threadIdx.x; e < E; e += stride)
        atomicAdd(&deg[dst[e]], 1);
}

// ---------------------------------------------------------------------------
// K2: single-block chunked exclusive scan -> rowptr, cursor; also dinv = deg^-1/2
__global__ __launch_bounds__(1024) void k_scan(const int* __restrict__ deg,
                                               int* __restrict__ rowptr,
                                               int* __restrict__ cursor,
                                               float* __restrict__ dinv, int n) {
    __shared__ int sdata[1024];
    __shared__ int carry_s;
    int tid = threadIdx.x;
    if (tid == 0) carry_s = 0;
    __syncthreads();
    for (int base = 0; base < n; base += 1024) {
        int i = base + tid;
        int v = (i < n) ? deg[i] : 0;
        sdata[tid] = v;
        __syncthreads();
        for (int off = 1; off < 1024; off <<= 1) {
            int t = (tid >= off) ? sdata[tid - off] : 0;
            __syncthreads();
            sdata[tid] += t;
            __syncthreads();
        }
        int incl = sdata[tid];
        int carry = carry_s;
        if (i < n) {
            int excl = carry + incl - v;
            rowptr[i] = excl;
            cursor[i] = excl;
            dinv[i] = (v > 0) ? rsqrtf((float)v) : 0.0f;
        }
        __syncthreads();
        if (tid == 1023) carry_s = carry + incl;
        __syncthreads();
    }
    if (tid == 0) rowptr[n] = carry_s;
}

// ---------------------------------------------------------------------------
// K3: scatter edges into CSR order (by dst); adj = dinv[src]*dinv[dst]
__global__ void k_scatter(const int* __restrict__ src, const int* __restrict__ dst,
                          const float* __restrict__ dinv, int* __restrict__ cursor,
                          int* __restrict__ srcp, float* __restrict__ adjp, int E) {
    int stride = gridDim.x * blockDim.x;
    for (int e = blockIdx.x * blockDim.x + threadIdx.x; e < E; e += stride) {
        int d = dst[e], sN = src[e];
        int k = atomicAdd(&cursor[d], 1);
        srcp[k] = sN;
        adjp[k] = dinv[sN] * dinv[d];
    }
}

// ---------------------------------------------------------------------------
// K4: sparse_v = sign(w) * relu(|w| - sigmoid(s))
__global__ void k_sparse(const float* __restrict__ w, const float* __restrict__ s,
                         float* __restrict__ h0, int total4) {
    float t = 1.0f / (1.0f + expf(-s[0]));
    int stride = gridDim.x * blockDim.x;
    for (int i = blockIdx.x * blockDim.x + threadIdx.x; i < total4; i += stride) {
        float4 v = ((const float4*)w)[i];
        float4 r;
        r.x = copysignf(fmaxf(fabsf(v.x) - t, 0.0f), v.x);
        r.y = copysignf(fmaxf(fabsf(v.y) - t, 0.0f), v.y);
        r.z = copysignf(fmaxf(fabsf(v.z) - t, 0.0f), v.z);
        r.w = copysignf(fmaxf(fabsf(v.w) - t, 0.0f), v.w);
        ((float4*)h0)[i] = r;
    }
}

// ---------------------------------------------------------------------------
// K5: init sampled-row accumulator with sparse_v rows; also reg sum of ego rows
__global__ void k_samp_init(const float* __restrict__ h, const float* __restrict__ w,
                            const int* __restrict__ users, const int* __restrict__ pos,
                            const int* __restrict__ neg, float* __restrict__ samp,
                            float* __restrict__ partials, int B) {
    int g = blockIdx.x * blockDim.x + threadIdx.x;
    int j = g >> 4, l = g & 15;
    if (j >= 3 * B) return;
    int idx = (j < B) ? users[j] : ((j < 2 * B) ? pos[j - B] : neg[j - 2 * B]);
    float4 v = *(const float4*)(h + (size_t)idx * 64 + l * 4);
    *(float4*)(samp + (size_t)j * 64 + l * 4) = v;
    float4 e = *(const float4*)(w + (size_t)idx * 64 + l * 4);
    float ss = e.x * e.x + e.y * e.y + e.z * e.z + e.w * e.w;
    for (int m = 1; m < 16; m <<= 1) ss += __shfl_xor(ss, m);
    if (l == 0) atomicAdd(&partials[0], ss);
}

// K7: add h rows at sample indices
__global__ void k_samp_add(const float* __restrict__ h,
                           const int* __restrict__ users, const int* __restrict__ pos,
                           const int* __restrict__ neg, float* __restrict__ samp, int B) {
    int g = blockIdx.x * blockDim.x + threadIdx.x;
    int j = g >> 4, l = g & 15;
    if (j >= 3 * B) return;
    int idx = (j < B) ? users[j] : ((j < 2 * B) ? pos[j - B] : neg[j - 2 * B]);
    float4 v = *(const float4*)(h + (size_t)idx * 64 + l * 4);
    float4 a = *(float4*)(samp + (size_t)j * 64 + l * 4);
    a.x += v.x; a.y += v.y; a.z += v.z; a.w += v.w;
    *(float4*)(samp + (size_t)j * 64 + l * 4) = a;
}

// ---------------------------------------------------------------------------
// K6: SpMM  hout[n] = sum_{k in row n} adjp[k] * hin[srcp[k]]
//     one node per 16-lane group; each lane owns a float4 of the 64-dim row
__global__ void k_spmm(const float* __restrict__ hin, float* __restrict__ hout,
                       const int* __restrict__ rowptr, const int* __restrict__ srcp,
                       const float* __restrict__ adjp, int n) {
    int g = blockIdx.x * blockDim.x + threadIdx.x;
    int node = g >> 4, l = g & 15;
    if (node >= n) return;
    int beg = rowptr[node], end = rowptr[node + 1];
    float4 acc = make_float4(0.f, 0.f, 0.f, 0.f);
    for (int k = beg; k < end; ++k) {
        int sN = srcp[k];
        float a = adjp[k];
        float4 v = *(const float4*)(hin + (size_t)sN * 64 + l * 4);
        acc.x = fmaf(a, v.x, acc.x);
        acc.y = fmaf(a, v.y, acc.y);
        acc.z = fmaf(a, v.z, acc.z);
        acc.w = fmaf(a, v.w, acc.w);
    }
    *(float4*)(hout + (size_t)node * 64 + l * 4) = acc;
}

// ---------------------------------------------------------------------------
// K8: BPR scores: per sample, dot(users, pos) and dot(users, neg) over acc/4
__global__ void k_scores(const float* __restrict__ samp, float* __restrict__ partials,
                         int B) {
    int g = blockIdx.x * blockDim.x + threadIdx.x;
    int j = g >> 4, l = g & 15;
    if (j >= B) return;
    float4 u = *(const float4*)(samp + (size_t)j * 64 + l * 4);
    float4 p = *(const float4*)(samp + (size_t)(j + B) * 64 + l * 4);
    float4 q = *(const float4*)(samp + (size_t)(j + 2 * B) * 64 + l * 4);
    float ps = u.x * p.x + u.y * p.y + u.z * p.z + u.w * p.w;
    float ns = u.x * q.x + u.y * q.y + u.z * q.z + u.w * q.w;
    for (int m = 1; m < 16; m <<= 1) {
        ps += __shfl_xor(ps, m);
        ns += __shfl_xor(ns, m);
    }
    if (l == 0) {
        // all_emb = acc/4 -> scores scale by 1/16
        float x = (ns - ps) * 0.0625f;
        float sp = fmaxf(x, 0.0f) + log1pf(expf(-fabsf(x)));  // stable softplus
        atomicAdd(&partials[1], sp);
    }
}

// ---------------------------------------------------------------------------
// K9: finalize the 4 scalar outputs
__global__ void k_final(const float* __restrict__ partials, const float* __restrict__ s,
                        float* __restrict__ out, int B) {
    float b = (float)B;
    float loss_emb = partials[1] / b;
    float reg_loss = 0.5f * partials[0] / b * 1e-4f;
    float s0 = s[0];
    float s_loss = 0.5f * s0 * s0 / b * 1e-4f;
    out[0] = loss_emb + reg_loss + s_loss;
    out[1] = loss_emb;
    out[2] = reg_loss;
    out[3] = s_loss;
}

// ---------------------------------------------------------------------------
extern "C" void kernel_launch(void* const* d_in, const int* in_sizes, int n_in,
                              void* d_out, int out_size, void* d_ws, size_t ws_size,
                              hipStream_t stream) {
    const float* weight = (const float*)d_in[0];
    const float* s      = (const float*)d_in[1];
    const int*   src    = (const int*)d_in[2];
    const int*   dst    = (const int*)d_in[3];
    const int*   users  = (const int*)d_in[4];
    const int*   pos    = (const int*)d_in[5];
    const int*   neg    = (const int*)d_in[6];

    const int D = 64;
    const int N = in_sizes[0] / D;
    const int E = in_sizes[2];
    const int B = in_sizes[4];

    // bump allocator over d_ws (256B aligned)
    char* wp = (char*)d_ws;
    auto alloc = [&](size_t bytes) -> void* {
        void* p = (void*)wp;
        wp += (bytes + 255) & ~(size_t)255;
        return p;
    };
    int*   deg     = (int*)alloc((size_t)N * 4);
    float* dinv    = (float*)alloc((size_t)N * 4);
    int*   rowptr  = (int*)alloc((size_t)(N + 1) * 4);
    int*   cursor  = (int*)alloc((size_t)N * 4);
    int*   srcp    = (int*)alloc((size_t)E * 4);
    float* adjp    = (float*)alloc((size_t)E * 4);
    float* h0      = (float*)alloc((size_t)N * D * 4);
    float* h1      = (float*)alloc((size_t)N * D * 4);
    float* samp    = (float*)alloc((size_t)3 * B * D * 4);
    float* partials= (float*)alloc(256);

    hipMemsetAsync(deg, 0, (size_t)N * 4, stream);
    hipMemsetAsync(partials, 0, 32, stream);

    k_hist<<<2048, 256, 0, stream>>>(dst, deg, E);
    k_scan<<<1, 1024, 0, stream>>>(deg, rowptr, cursor, dinv, N);
    k_scatter<<<2048, 256, 0, stream>>>(src, dst, dinv, cursor, srcp, adjp, E);
    k_sparse<<<2048, 256, 0, stream>>>(weight, s, h0, N * D / 4);
    k_samp_init<<<CDIV(3 * B * 16, 256), 256, 0, stream>>>(h0, weight, users, pos, neg,
                                                           samp, partials, B);
    float* hin = h0;
    float* hout = h1;
    for (int layer = 0; layer < 3; ++layer) {
        k_spmm<<<CDIV(N * 16, 256), 256, 0, stream>>>(hin, hout, rowptr, srcp, adjp, N);
        k_samp_add<<<CDIV(3 * B * 16, 256), 256, 0, stream>>>(hout, users, pos, neg,
                                                              samp, B);
        float* t = hin; hin = hout; hout = t;
    }
    k_scores<<<CDIV(B * 16, 256), 256, 0, stream>>>(samp, partials, B);
    k_final<<<1, 1, 0, stream>>>(partials, s, (float*)d_out, B);
}

// Round 2
// 488.642 us; speedup vs baseline: 1.3442x; 1.3442x over previous
//
#include <hip/hip_runtime.h>
#include <math.h>

#define CDIV(a,b) (((a)+(b)-1)/(b))

// ---------------------------------------------------------------------------
// K1: in-degree histogram over dst
__global__ void k_hist(const int* __restrict__ dst, int* __restrict__ deg, int E) {
    int stride = gridDim.x * blockDim.x;
    for (int e = blockIdx.x * blockDim.x + threadIdx.x; e < E; e += stride)
        atomicAdd(&deg[dst[e]], 1);
}

// ---------------------------------------------------------------------------
// Multi-block scan: CHUNK = 4096 elements per block (1024 thr x 4)
// K2a: per-block sum of deg chunk
__global__ __launch_bounds__(1024) void k_scan_reduce(const int* __restrict__ deg,
                                                      int* __restrict__ blockSums, int n) {
    __shared__ int wsum[16];
    int tid = threadIdx.x;
    int base = blockIdx.x * 4096 + tid * 4;
    int s = 0;
    if (base + 3 < n) {
        int4 v = *(const int4*)(deg + base);
        s = v.x + v.y + v.z + v.w;
    } else {
        for (int k = 0; k < 4; ++k) if (base + k < n) s += deg[base + k];
    }
    for (int m = 1; m < 64; m <<= 1) s += __shfl_xor(s, m);
    int wid = tid >> 6;
    if ((tid & 63) == 0) wsum[wid] = s;
    __syncthreads();
    if (tid == 0) {
        int t = 0;
        for (int w = 0; w < 16; ++w) t += wsum[w];
        blockSums[blockIdx.x] = t;
    }
}

// K2b: exclusive scan of block sums (nb <= 1024), single block; sets rowptr[n]=total
__global__ __launch_bounds__(1024) void k_scan_blocks(int* __restrict__ blockSums,
                                                      int* __restrict__ rowptr,
                                                      int nb, int n) {
    __shared__ int sdata[1024];
    int tid = threadIdx.x;
    int v = (tid < nb) ? blockSums[tid] : 0;
    sdata[tid] = v;
    __syncthreads();
    for (int off = 1; off < 1024; off <<= 1) {
        int t = (tid >= off) ? sdata[tid - off] : 0;
        __syncthreads();
        sdata[tid] += t;
        __syncthreads();
    }
    if (tid < nb) blockSums[tid] = sdata[tid] - v;  // exclusive
    if (tid == 1023) rowptr[n] = sdata[1023];       // total = E
}

// K2c: block-local exclusive scan + block offset -> rowptr, cursor, dinv
__global__ __launch_bounds__(1024) void k_scan_final(const int* __restrict__ deg,
                                                     const int* __restrict__ blockSums,
                                                     int* __restrict__ rowptr,
                                                     int* __restrict__ cursor,
                                                     float* __restrict__ dinv, int n) {
    __shared__ int wsum[16];
    int tid = threadIdx.x;
    int lane = tid & 63, wid = tid >> 6;
    int base = blockIdx.x * 4096 + tid * 4;
    int v0 = 0, v1 = 0, v2 = 0, v3 = 0;
    if (base + 3 < n) {
        int4 v = *(const int4*)(deg + base);
        v0 = v.x; v1 = v.y; v2 = v.z; v3 = v.w;
    } else {
        if (base + 0 < n) v0 = deg[base + 0];
        if (base + 1 < n) v1 = deg[base + 1];
        if (base + 2 < n) v2 = deg[base + 2];
        if (base + 3 < n) v3 = deg[base + 3];
    }
    int tot = v0 + v1 + v2 + v3;
    // wave inclusive scan of tot
    int incl = tot;
    for (int off = 1; off < 64; off <<= 1) {
        int t = __shfl_up(incl, off);
        if (lane >= off) incl += t;
    }
    if (lane == 63) wsum[wid] = incl;
    __syncthreads();
    int wave_prefix = 0;
    for (int w = 0; w < wid; ++w) wave_prefix += wsum[w];
    int excl = blockSums[blockIdx.x] + wave_prefix + (incl - tot);
    // element-wise exclusive offsets
    int e0 = excl, e1 = e0 + v0, e2 = e1 + v1, e3 = e2 + v2;
    if (base + 0 < n) { rowptr[base+0] = e0; cursor[base+0] = e0; dinv[base+0] = v0 > 0 ? rsqrtf((float)v0) : 0.0f; }
    if (base + 1 < n) { rowptr[base+1] = e1; cursor[base+1] = e1; dinv[base+1] = v1 > 0 ? rsqrtf((float)v1) : 0.0f; }
    if (base + 2 < n) { rowptr[base+2] = e2; cursor[base+2] = e2; dinv[base+2] = v2 > 0 ? rsqrtf((float)v2) : 0.0f; }
    if (base + 3 < n) { rowptr[base+3] = e3; cursor[base+3] = e3; dinv[base+3] = v3 > 0 ? rsqrtf((float)v3) : 0.0f; }
}

// ---------------------------------------------------------------------------
// K3: scatter edges into CSR order (by dst); adj = dinv[src]*dinv[dst]
__global__ void k_scatter(const int* __restrict__ src, const int* __restrict__ dst,
                          const float* __restrict__ dinv, int* __restrict__ cursor,
                          int* __restrict__ srcp, float* __restrict__ adjp, int E) {
    int stride = gridDim.x * blockDim.x;
    for (int e = blockIdx.x * blockDim.x + threadIdx.x; e < E; e += stride) {
        int d = dst[e], sN = src[e];
        int k = atomicAdd(&cursor[d], 1);
        srcp[k] = sN;
        adjp[k] = dinv[sN] * dinv[d];
    }
}

// ---------------------------------------------------------------------------
// K4: sparse_v = sign(w) * relu(|w| - sigmoid(s))
__global__ void k_sparse(const float* __restrict__ w, const float* __restrict__ s,
                         float* __restrict__ h0, int total4) {
    float t = 1.0f / (1.0f + expf(-s[0]));
    int stride = gridDim.x * blockDim.x;
    for (int i = blockIdx.x * blockDim.x + threadIdx.x; i < total4; i += stride) {
        float4 v = ((const float4*)w)[i];
        float4 r;
        r.x = copysignf(fmaxf(fabsf(v.x) - t, 0.0f), v.x);
        r.y = copysignf(fmaxf(fabsf(v.y) - t, 0.0f), v.y);
        r.z = copysignf(fmaxf(fabsf(v.z) - t, 0.0f), v.z);
        r.w = copysignf(fmaxf(fabsf(v.w) - t, 0.0f), v.w);
        ((float4*)h0)[i] = r;
    }
}

// ---------------------------------------------------------------------------
// K5: init sampled-row accumulator with sparse_v rows; also reg sum of ego rows
__global__ void k_samp_init(const float* __restrict__ h, const float* __restrict__ w,
                            const int* __restrict__ users, const int* __restrict__ pos,
                            const int* __restrict__ neg, float* __restrict__ samp,
                            float* __restrict__ partials, int B) {
    int g = blockIdx.x * blockDim.x + threadIdx.x;
    int j = g >> 4, l = g & 15;
    if (j >= 3 * B) return;
    int idx = (j < B) ? users[j] : ((j < 2 * B) ? pos[j - B] : neg[j - 2 * B]);
    float4 v = *(const float4*)(h + (size_t)idx * 64 + l * 4);
    *(float4*)(samp + (size_t)j * 64 + l * 4) = v;
    float4 e = *(const float4*)(w + (size_t)idx * 64 + l * 4);
    float ss = e.x * e.x + e.y * e.y + e.z * e.z + e.w * e.w;
    for (int m = 1; m < 16; m <<= 1) ss += __shfl_xor(ss, m);
    if (l == 0) atomicAdd(&partials[0], ss);
}

// K7: add h rows at sample indices
__global__ void k_samp_add(const float* __restrict__ h,
                           const int* __restrict__ users, const int* __restrict__ pos,
                           const int* __restrict__ neg, float* __restrict__ samp, int B) {
    int g = blockIdx.x * blockDim.x + threadIdx.x;
    int j = g >> 4, l = g & 15;
    if (j >= 3 * B) return;
    int idx = (j < B) ? users[j] : ((j < 2 * B) ? pos[j - B] : neg[j - 2 * B]);
    float4 v = *(const float4*)(h + (size_t)idx * 64 + l * 4);
    float4 a = *(float4*)(samp + (size_t)j * 64 + l * 4);
    a.x += v.x; a.y += v.y; a.z += v.z; a.w += v.w;
    *(float4*)(samp + (size_t)j * 64 + l * 4) = a;
}

// ---------------------------------------------------------------------------
// K6: SpMM  hout[n] = sum_{k in row n} adjp[k] * hin[srcp[k]]
//     one node per 16-lane group; each lane owns a float4 of the 64-dim row
__global__ void k_spmm(const float* __restrict__ hin, float* __restrict__ hout,
                       const int* __restrict__ rowptr, const int* __restrict__ srcp,
                       const float* __restrict__ adjp, int n) {
    int g = blockIdx.x * blockDim.x + threadIdx.x;
    int node = g >> 4, l = g & 15;
    if (node >= n) return;
    int beg = rowptr[node], end = rowptr[node + 1];
    float4 acc = make_float4(0.f, 0.f, 0.f, 0.f);
    for (int k = beg; k < end; ++k) {
        int sN = srcp[k];
        float a = adjp[k];
        float4 v = *(const float4*)(hin + (size_t)sN * 64 + l * 4);
        acc.x = fmaf(a, v.x, acc.x);
        acc.y = fmaf(a, v.y, acc.y);
        acc.z = fmaf(a, v.z, acc.z);
        acc.w = fmaf(a, v.w, acc.w);
    }
    *(float4*)(hout + (size_t)node * 64 + l * 4) = acc;
}

// ---------------------------------------------------------------------------
// K8: BPR scores: per sample, dot(users, pos) and dot(users, neg) over acc/4
__global__ void k_scores(const float* __restrict__ samp, float* __restrict__ partials,
                         int B) {
    int g = blockIdx.x * blockDim.x + threadIdx.x;
    int j = g >> 4, l = g & 15;
    if (j >= B) return;
    float4 u = *(const float4*)(samp + (size_t)j * 64 + l * 4);
    float4 p = *(const float4*)(samp + (size_t)(j + B) * 64 + l * 4);
    float4 q = *(const float4*)(samp + (size_t)(j + 2 * B) * 64 + l * 4);
    float ps = u.x * p.x + u.y * p.y + u.z * p.z + u.w * p.w;
    float ns = u.x * q.x + u.y * q.y + u.z * q.z + u.w * q.w;
    for (int m = 1; m < 16; m <<= 1) {
        ps += __shfl_xor(ps, m);
        ns += __shfl_xor(ns, m);
    }
    if (l == 0) {
        // all_emb = acc/4 -> scores scale by 1/16
        float x = (ns - ps) * 0.0625f;
        float sp = fmaxf(x, 0.0f) + log1pf(expf(-fabsf(x)));  // stable softplus
        atomicAdd(&partials[1], sp);
    }
}

// ---------------------------------------------------------------------------
// K9: finalize the 4 scalar outputs
__global__ void k_final(const float* __restrict__ partials, const float* __restrict__ s,
                        float* __restrict__ out, int B) {
    float b = (float)B;
    float loss_emb = partials[1] / b;
    float reg_loss = 0.5f * partials[0] / b * 1e-4f;
    float s0 = s[0];
    float s_loss = 0.5f * s0 * s0 / b * 1e-4f;
    out[0] = loss_emb + reg_loss + s_loss;
    out[1] = loss_emb;
    out[2] = reg_loss;
    out[3] = s_loss;
}

// ---------------------------------------------------------------------------
extern "C" void kernel_launch(void* const* d_in, const int* in_sizes, int n_in,
                              void* d_out, int out_size, void* d_ws, size_t ws_size,
                              hipStream_t stream) {
    const float* weight = (const float*)d_in[0];
    const float* s      = (const float*)d_in[1];
    const int*   src    = (const int*)d_in[2];
    const int*   dst    = (const int*)d_in[3];
    const int*   users  = (const int*)d_in[4];
    const int*   pos    = (const int*)d_in[5];
    const int*   neg    = (const int*)d_in[6];

    const int D = 64;
    const int N = in_sizes[0] / D;
    const int E = in_sizes[2];
    const int B = in_sizes[4];
    const int NB = CDIV(N, 4096);

    // bump allocator over d_ws (256B aligned)
    char* wp = (char*)d_ws;
    auto alloc = [&](size_t bytes) -> void* {
        void* p = (void*)wp;
        wp += (bytes + 255) & ~(size_t)255;
        return p;
    };
    int*   deg      = (int*)alloc((size_t)N * 4);
    float* dinv     = (float*)alloc((size_t)N * 4);
    int*   rowptr   = (int*)alloc((size_t)(N + 1) * 4);
    int*   cursor   = (int*)alloc((size_t)N * 4);
    int*   blockSums= (int*)alloc((size_t)1024 * 4);
    int*   srcp     = (int*)alloc((size_t)E * 4);
    float* adjp     = (float*)alloc((size_t)E * 4);
    float* h0       = (float*)alloc((size_t)N * D * 4);
    float* h1       = (float*)alloc((size_t)N * D * 4);
    float* samp     = (float*)alloc((size_t)3 * B * D * 4);
    float* partials = (float*)alloc(256);

    hipMemsetAsync(deg, 0, (size_t)N * 4, stream);
    hipMemsetAsync(partials, 0, 32, stream);

    k_hist<<<2048, 256, 0, stream>>>(dst, deg, E);
    k_scan_reduce<<<NB, 1024, 0, stream>>>(deg, blockSums, N);
    k_scan_blocks<<<1, 1024, 0, stream>>>(blockSums, rowptr, NB, N);
    k_scan_final<<<NB, 1024, 0, stream>>>(deg, blockSums, rowptr, cursor, dinv, N);
    k_scatter<<<2048, 256, 0, stream>>>(src, dst, dinv, cursor, srcp, adjp, E);
    k_sparse<<<2048, 256, 0, stream>>>(weight, s, h0, N * D / 4);
    k_samp_init<<<CDIV(3 * B * 16, 256), 256, 0, stream>>>(h0, weight, users, pos, neg,
                                                           samp, partials, B);
    float* hin = h0;
    float* hout = h1;
    for (int layer = 0; layer < 3; ++layer) {
        k_spmm<<<CDIV(N * 16, 256), 256, 0, stream>>>(hin, hout, rowptr, srcp, adjp, N);
        k_samp_add<<<CDIV(3 * B * 16, 256), 256, 0, stream>>>(hout, users, pos, neg,
                                                              samp, B);
        float* t = hin; hin = hout; hout = t;
    }
    k_scores<<<CDIV(B * 16, 256), 256, 0, stream>>>(samp, partials, B);
    k_final<<<1, 1, 0, stream>>>(partials, s, (float*)d_out, B);
}

// Round 3
// 101.676 us; speedup vs baseline: 6.4602x; 4.8059x over previous
//
#include <hip/hip_runtime.h>
#include <math.h>

#define CDIV(a,b) (((a)+(b)-1)/(b))

// Device-side gate: when the sparse embedding has zero nonzero rows, every
// propagation output is exactly zero and unobservable downstream (samp rows
// are initialized from h0 and never incremented), so these kernels may exit.
#define GATE_ON_EMPTY(nnzCount) do { if (*(nnzCount) == 0) return; } while (0)

// ---------------------------------------------------------------------------
// K1: in-degree histogram over dst
__global__ void k_hist(const int* __restrict__ dst, int* __restrict__ deg, int E,
                       const int* __restrict__ nnzCount) {
    GATE_ON_EMPTY(nnzCount);
    int stride = gridDim.x * blockDim.x;
    for (int e = blockIdx.x * blockDim.x + threadIdx.x; e < E; e += stride)
        atomicAdd(&deg[dst[e]], 1);
}

// ---------------------------------------------------------------------------
// Multi-block scan: CHUNK = 4096 elements per block (1024 thr x 4)
// K2a: per-block sum of deg chunk
__global__ __launch_bounds__(1024) void k_scan_reduce(const int* __restrict__ deg,
                                                      int* __restrict__ blockSums, int n,
                                                      const int* __restrict__ nnzCount) {
    GATE_ON_EMPTY(nnzCount);
    __shared__ int wsum[16];
    int tid = threadIdx.x;
    int base = blockIdx.x * 4096 + tid * 4;
    int s = 0;
    if (base + 3 < n) {
        int4 v = *(const int4*)(deg + base);
        s = v.x + v.y + v.z + v.w;
    } else {
        for (int k = 0; k < 4; ++k) if (base + k < n) s += deg[base + k];
    }
    for (int m = 1; m < 64; m <<= 1) s += __shfl_xor(s, m);
    int wid = tid >> 6;
    if ((tid & 63) == 0) wsum[wid] = s;
    __syncthreads();
    if (tid == 0) {
        int t = 0;
        for (int w = 0; w < 16; ++w) t += wsum[w];
        blockSums[blockIdx.x] = t;
    }
}

// K2b: exclusive scan of block sums (nb <= 1024), single block; sets rowptr[n]=total
__global__ __launch_bounds__(1024) void k_scan_blocks(int* __restrict__ blockSums,
                                                      int* __restrict__ rowptr,
                                                      int nb, int n,
                                                      const int* __restrict__ nnzCount) {
    GATE_ON_EMPTY(nnzCount);
    __shared__ int sdata[1024];
    int tid = threadIdx.x;
    int v = (tid < nb) ? blockSums[tid] : 0;
    sdata[tid] = v;
    __syncthreads();
    for (int off = 1; off < 1024; off <<= 1) {
        int t = (tid >= off) ? sdata[tid - off] : 0;
        __syncthreads();
        sdata[tid] += t;
        __syncthreads();
    }
    if (tid < nb) blockSums[tid] = sdata[tid] - v;  // exclusive
    if (tid == 1023) rowptr[n] = sdata[1023];       // total = E
}

// K2c: block-local exclusive scan + block offset -> rowptr, cursor, dinv
__global__ __launch_bounds__(1024) void k_scan_final(const int* __restrict__ deg,
                                                     const int* __restrict__ blockSums,
                                                     int* __restrict__ rowptr,
                                                     int* __restrict__ cursor,
                                                     float* __restrict__ dinv, int n,
                                                     const int* __restrict__ nnzCount) {
    GATE_ON_EMPTY(nnzCount);
    __shared__ int wsum[16];
    int tid = threadIdx.x;
    int lane = tid & 63, wid = tid >> 6;
    int base = blockIdx.x * 4096 + tid * 4;
    int v0 = 0, v1 = 0, v2 = 0, v3 = 0;
    if (base + 3 < n) {
        int4 v = *(const int4*)(deg + base);
        v0 = v.x; v1 = v.y; v2 = v.z; v3 = v.w;
    } else {
        if (base + 0 < n) v0 = deg[base + 0];
        if (base + 1 < n) v1 = deg[base + 1];
        if (base + 2 < n) v2 = deg[base + 2];
        if (base + 3 < n) v3 = deg[base + 3];
    }
    int tot = v0 + v1 + v2 + v3;
    int incl = tot;
    for (int off = 1; off < 64; off <<= 1) {
        int t = __shfl_up(incl, off);
        if (lane >= off) incl += t;
    }
    if (lane == 63) wsum[wid] = incl;
    __syncthreads();
    int wave_prefix = 0;
    for (int w = 0; w < wid; ++w) wave_prefix += wsum[w];
    int excl = blockSums[blockIdx.x] + wave_prefix + (incl - tot);
    int e0 = excl, e1 = e0 + v0, e2 = e1 + v1, e3 = e2 + v2;
    if (base + 0 < n) { rowptr[base+0] = e0; cursor[base+0] = e0; dinv[base+0] = v0 > 0 ? rsqrtf((float)v0) : 0.0f; }
    if (base + 1 < n) { rowptr[base+1] = e1; cursor[base+1] = e1; dinv[base+1] = v1 > 0 ? rsqrtf((float)v1) : 0.0f; }
    if (base + 2 < n) { rowptr[base+2] = e2; cursor[base+2] = e2; dinv[base+2] = v2 > 0 ? rsqrtf((float)v2) : 0.0f; }
    if (base + 3 < n) { rowptr[base+3] = e3; cursor[base+3] = e3; dinv[base+3] = v3 > 0 ? rsqrtf((float)v3) : 0.0f; }
}

// ---------------------------------------------------------------------------
// K3: scatter edges into CSR order (by dst); payload packed 8B = (src, adj)
__global__ void k_scatter(const int* __restrict__ src, const int* __restrict__ dst,
                          const float* __restrict__ dinv, int* __restrict__ cursor,
                          int2* __restrict__ edgep, int E,
                          const int* __restrict__ nnzCount) {
    GATE_ON_EMPTY(nnzCount);
    int stride = gridDim.x * blockDim.x;
    for (int e = blockIdx.x * blockDim.x + threadIdx.x; e < E; e += stride) {
        int d = dst[e], sN = src[e];
        int k = atomicAdd(&cursor[d], 1);
        float a = dinv[sN] * dinv[d];
        edgep[k] = make_int2(sN, __float_as_int(a));
    }
}

// ---------------------------------------------------------------------------
// K4: sparse_v = sign(w) * relu(|w| - sigmoid(s)); per-row nonzero flag + count
//     one row (64 f32) per 16-lane group, float4 per lane
__global__ void k_sparse_flag(const float* __restrict__ w, const float* __restrict__ s,
                              float* __restrict__ h0, int* __restrict__ rowNnz,
                              int* __restrict__ nnzCount, int N) {
    int g = blockIdx.x * blockDim.x + threadIdx.x;
    int node = g >> 4, l = g & 15;
    if (node >= N) return;
    float t = 1.0f / (1.0f + expf(-s[0]));
    size_t off = (size_t)node * 64 + l * 4;
    float4 v = *(const float4*)(w + off);
    float4 r;
    r.x = copysignf(fmaxf(fabsf(v.x) - t, 0.0f), v.x);
    r.y = copysignf(fmaxf(fabsf(v.y) - t, 0.0f), v.y);
    r.z = copysignf(fmaxf(fabsf(v.z) - t, 0.0f), v.z);
    r.w = copysignf(fmaxf(fabsf(v.w) - t, 0.0f), v.w);
    *(float4*)(h0 + off) = r;
    int nz = (r.x != 0.0f) | (r.y != 0.0f) | (r.z != 0.0f) | (r.w != 0.0f);
    for (int m = 1; m < 16; m <<= 1) nz |= __shfl_xor(nz, m);
    if (l == 0) {
        rowNnz[node] = nz;
        if (nz) atomicAdd(nnzCount, 1);
    }
}

// ---------------------------------------------------------------------------
// K5: init sampled-row accumulator with sparse_v rows; also reg sum of ego rows
__global__ void k_samp_init(const float* __restrict__ h, const float* __restrict__ w,
                            const int* __restrict__ users, const int* __restrict__ pos,
                            const int* __restrict__ neg, float* __restrict__ samp,
                            float* __restrict__ partials, int B) {
    int g = blockIdx.x * blockDim.x + threadIdx.x;
    int j = g >> 4, l = g & 15;
    if (j >= 3 * B) return;
    int idx = (j < B) ? users[j] : ((j < 2 * B) ? pos[j - B] : neg[j - 2 * B]);
    float4 v = *(const float4*)(h + (size_t)idx * 64 + l * 4);
    *(float4*)(samp + (size_t)j * 64 + l * 4) = v;
    float4 e = *(const float4*)(w + (size_t)idx * 64 + l * 4);
    float ss = e.x * e.x + e.y * e.y + e.z * e.z + e.w * e.w;
    for (int m = 1; m < 16; m <<= 1) ss += __shfl_xor(ss, m);
    if (l == 0) atomicAdd(&partials[0], ss);
}

// K7: add h rows at sample indices
__global__ void k_samp_add(const float* __restrict__ h,
                           const int* __restrict__ users, const int* __restrict__ pos,
                           const int* __restrict__ neg, float* __restrict__ samp, int B,
                           const int* __restrict__ nnzCount) {
    GATE_ON_EMPTY(nnzCount);
    int g = blockIdx.x * blockDim.x + threadIdx.x;
    int j = g >> 4, l = g & 15;
    if (j >= 3 * B) return;
    int idx = (j < B) ? users[j] : ((j < 2 * B) ? pos[j - B] : neg[j - 2 * B]);
    float4 v = *(const float4*)(h + (size_t)idx * 64 + l * 4);
    float4 a = *(float4*)(samp + (size_t)j * 64 + l * 4);
    a.x += v.x; a.y += v.y; a.z += v.z; a.w += v.w;
    *(float4*)(samp + (size_t)j * 64 + l * 4) = a;
}

// ---------------------------------------------------------------------------
// K6: SpMM  hout[n] = sum_{k in row n} adj_k * hin[src_k]
//     one node per 16-lane group; skips rows whose sparse source is all-zero
__global__ void k_spmm(const float* __restrict__ hin, float* __restrict__ hout,
                       const int* __restrict__ rowptr, const int2* __restrict__ edgep,
                       const int* __restrict__ rowNnz, int n,
                       const int* __restrict__ nnzCount) {
    GATE_ON_EMPTY(nnzCount);
    int g = blockIdx.x * blockDim.x + threadIdx.x;
    int node = g >> 4, l = g & 15;
    if (node >= n) return;
    int beg = rowptr[node], end = rowptr[node + 1];
    float4 acc = make_float4(0.f, 0.f, 0.f, 0.f);
    for (int k = beg; k < end; ++k) {
        int2 ep = edgep[k];
        int sN = ep.x;
        if (!rowNnz[sN]) continue;   // uniform across the 16-lane group
        float a = __int_as_float(ep.y);
        float4 v = *(const float4*)(hin + (size_t)sN * 64 + l * 4);
        acc.x = fmaf(a, v.x, acc.x);
        acc.y = fmaf(a, v.y, acc.y);
        acc.z = fmaf(a, v.z, acc.z);
        acc.w = fmaf(a, v.w, acc.w);
    }
    *(float4*)(hout + (size_t)node * 64 + l * 4) = acc;
}

// NOTE: rowNnz tracks sparsity of the LAYER-0 input only; h after one hop can
// be nonzero at rows whose sparse_v row was zero. So the per-edge skip is only
// valid for layer 0. Layers 1,2 use the unflagged variant.
__global__ void k_spmm_nf(const float* __restrict__ hin, float* __restrict__ hout,
                          const int* __restrict__ rowptr, const int2* __restrict__ edgep,
                          int n, const int* __restrict__ nnzCount) {
    GATE_ON_EMPTY(nnzCount);
    int g = blockIdx.x * blockDim.x + threadIdx.x;
    int node = g >> 4, l = g & 15;
    if (node >= n) return;
    int beg = rowptr[node], end = rowptr[node + 1];
    float4 acc = make_float4(0.f, 0.f, 0.f, 0.f);
    for (int k = beg; k < end; ++k) {
        int2 ep = edgep[k];
        int sN = ep.x;
        float a = __int_as_float(ep.y);
        float4 v = *(const float4*)(hin + (size_t)sN * 64 + l * 4);
        acc.x = fmaf(a, v.x, acc.x);
        acc.y = fmaf(a, v.y, acc.y);
        acc.z = fmaf(a, v.z, acc.z);
        acc.w = fmaf(a, v.w, acc.w);
    }
    *(float4*)(hout + (size_t)node * 64 + l * 4) = acc;
}

// ---------------------------------------------------------------------------
// K8: BPR scores
__global__ void k_scores(const float* __restrict__ samp, float* __restrict__ partials,
                         int B) {
    int g = blockIdx.x * blockDim.x + threadIdx.x;
    int j = g >> 4, l = g & 15;
    if (j >= B) return;
    float4 u = *(const float4*)(samp + (size_t)j * 64 + l * 4);
    float4 p = *(const float4*)(samp + (size_t)(j + B) * 64 + l * 4);
    float4 q = *(const float4*)(samp + (size_t)(j + 2 * B) * 64 + l * 4);
    float ps = u.x * p.x + u.y * p.y + u.z * p.z + u.w * p.w;
    float ns = u.x * q.x + u.y * q.y + u.z * q.z + u.w * q.w;
    for (int m = 1; m < 16; m <<= 1) {
        ps += __shfl_xor(ps, m);
        ns += __shfl_xor(ns, m);
    }
    if (l == 0) {
        float x = (ns - ps) * 0.0625f;  // all_emb = acc/4 -> score scale 1/16
        float sp = fmaxf(x, 0.0f) + log1pf(expf(-fabsf(x)));  // stable softplus
        atomicAdd(&partials[1], sp);
    }
}

// ---------------------------------------------------------------------------
// K9: finalize the 4 scalar outputs
__global__ void k_final(const float* __restrict__ partials, const float* __restrict__ s,
                        float* __restrict__ out, int B) {
    float b = (float)B;
    float loss_emb = partials[1] / b;
    float reg_loss = 0.5f * partials[0] / b * 1e-4f;
    float s0 = s[0];
    float s_loss = 0.5f * s0 * s0 / b * 1e-4f;
    out[0] = loss_emb + reg_loss + s_loss;
    out[1] = loss_emb;
    out[2] = reg_loss;
    out[3] = s_loss;
}

// ---------------------------------------------------------------------------
extern "C" void kernel_launch(void* const* d_in, const int* in_sizes, int n_in,
                              void* d_out, int out_size, void* d_ws, size_t ws_size,
                              hipStream_t stream) {
    const float* weight = (const float*)d_in[0];
    const float* s      = (const float*)d_in[1];
    const int*   src    = (const int*)d_in[2];
    const int*   dst    = (const int*)d_in[3];
    const int*   users  = (const int*)d_in[4];
    const int*   pos    = (const int*)d_in[5];
    const int*   neg    = (const int*)d_in[6];

    const int D = 64;
    const int N = in_sizes[0] / D;
    const int E = in_sizes[2];
    const int B = in_sizes[4];
    const int NB = CDIV(N, 4096);

    char* wp = (char*)d_ws;
    auto alloc = [&](size_t bytes) -> void* {
        void* p = (void*)wp;
        wp += (bytes + 255) & ~(size_t)255;
        return p;
    };
    int*   deg      = (int*)alloc((size_t)N * 4);
    float* dinv     = (float*)alloc((size_t)N * 4);
    int*   rowptr   = (int*)alloc((size_t)(N + 1) * 4);
    int*   cursor   = (int*)alloc((size_t)N * 4);
    int*   rowNnz   = (int*)alloc((size_t)N * 4);
    int*   blockSums= (int*)alloc((size_t)1024 * 4);
    int2*  edgep    = (int2*)alloc((size_t)E * 8);
    float* h0       = (float*)alloc((size_t)N * D * 4);
    float* h1       = (float*)alloc((size_t)N * D * 4);
    float* samp     = (float*)alloc((size_t)3 * B * D * 4);
    float* partials = (float*)alloc(256);
    int*   nnzCount = (int*)(partials + 8);

    hipMemsetAsync(deg, 0, (size_t)N * 4, stream);
    hipMemsetAsync(partials, 0, 64, stream);  // covers partials[0..1] + nnzCount

    // sparse embedding + row flags first: everything structural is gated on it
    k_sparse_flag<<<CDIV(N * 16, 256), 256, 0, stream>>>(weight, s, h0, rowNnz,
                                                         nnzCount, N);
    k_hist<<<2048, 256, 0, stream>>>(dst, deg, E, nnzCount);
    k_scan_reduce<<<NB, 1024, 0, stream>>>(deg, blockSums, N, nnzCount);
    k_scan_blocks<<<1, 1024, 0, stream>>>(blockSums, rowptr, NB, N, nnzCount);
    k_scan_final<<<NB, 1024, 0, stream>>>(deg, blockSums, rowptr, cursor, dinv, N,
                                          nnzCount);
    k_scatter<<<2048, 256, 0, stream>>>(src, dst, dinv, cursor, edgep, E, nnzCount);
    k_samp_init<<<CDIV(3 * B * 16, 256), 256, 0, stream>>>(h0, weight, users, pos, neg,
                                                           samp, partials, B);
    // layer 0: per-edge zero-row skip via rowNnz (valid only for sparse_v input)
    k_spmm<<<CDIV(N * 16, 256), 256, 0, stream>>>(h0, h1, rowptr, edgep, rowNnz, N,
                                                  nnzCount);
    k_samp_add<<<CDIV(3 * B * 16, 256), 256, 0, stream>>>(h1, users, pos, neg, samp, B,
                                                          nnzCount);
    // layers 1,2: no flags
    k_spmm_nf<<<CDIV(N * 16, 256), 256, 0, stream>>>(h1, h0, rowptr, edgep, N, nnzCount);
    k_samp_add<<<CDIV(3 * B * 16, 256), 256, 0, stream>>>(h0, users, pos, neg, samp, B,
                                                          nnzCount);
    k_spmm_nf<<<CDIV(N * 16, 256), 256, 0, stream>>>(h0, h1, rowptr, edgep, N, nnzCount);
    k_samp_add<<<CDIV(3 * B * 16, 256), 256, 0, stream>>>(h1, users, pos, neg, samp, B,
                                                          nnzCount);
    k_scores<<<CDIV(B * 16, 256), 256, 0, stream>>>(samp, partials, B);
    k_final<<<1, 1, 0, stream>>>(partials, s, (float*)d_out, B);
}

// Round 4
// 54.980 us; speedup vs baseline: 11.9471x; 1.8493x over previous
//
#include <hip/hip_runtime.h>
#include <math.h>

#define CDIV(a,b) (((a)+(b)-1)/(b))

// Device-side gate: when the sparse embedding has zero nonzero rows, every
// propagation output is exactly zero and unobservable downstream, so the
// structural/propagation kernels may exit immediately.
#define GATE_ON_EMPTY(nnzCount) do { if (*(nnzCount) == 0) return; } while (0)

// ---------------------------------------------------------------------------
// K1: in-degree histogram over dst
__global__ void k_hist(const int* __restrict__ dst, int* __restrict__ deg, int E,
                       const int* __restrict__ nnzCount) {
    GATE_ON_EMPTY(nnzCount);
    int stride = gridDim.x * blockDim.x;
    for (int e = blockIdx.x * blockDim.x + threadIdx.x; e < E; e += stride)
        atomicAdd(&deg[dst[e]], 1);
}

// ---------------------------------------------------------------------------
// Multi-block scan, CHUNK = 4096 elements per block (1024 thr x 4).
// K2a: per-block sums
__global__ __launch_bounds__(1024) void k_scan_reduce(const int* __restrict__ deg,
                                                      int* __restrict__ blockSums, int n,
                                                      const int* __restrict__ nnzCount) {
    GATE_ON_EMPTY(nnzCount);
    __shared__ int wsum[16];
    int tid = threadIdx.x;
    int base = blockIdx.x * 4096 + tid * 4;
    int s = 0;
    if (base + 3 < n) {
        int4 v = *(const int4*)(deg + base);
        s = v.x + v.y + v.z + v.w;
    } else {
        for (int k = 0; k < 4; ++k) if (base + k < n) s += deg[base + k];
    }
    for (int m = 1; m < 64; m <<= 1) s += __shfl_xor(s, m);
    int wid = tid >> 6;
    if ((tid & 63) == 0) wsum[wid] = s;
    __syncthreads();
    if (tid == 0) {
        int t = 0;
        for (int w = 0; w < 16; ++w) t += wsum[w];
        blockSums[blockIdx.x] = t;
    }
}

// K2b (fused): block-local scan + inline exclusive-prefix of blockSums (nb<=64)
__global__ __launch_bounds__(1024) void k_scan_final(const int* __restrict__ deg,
                                                     const int* __restrict__ blockSums,
                                                     int* __restrict__ rowptr,
                                                     int* __restrict__ cursor,
                                                     float* __restrict__ dinv,
                                                     int n, int nb,
                                                     const int* __restrict__ nnzCount) {
    GATE_ON_EMPTY(nnzCount);
    __shared__ int wsum[16];
    __shared__ int bsums[64];
    int tid = threadIdx.x;
    if (tid < 64) bsums[tid] = (tid < nb) ? blockSums[tid] : 0;
    int lane = tid & 63, wid = tid >> 6;
    int base = blockIdx.x * 4096 + tid * 4;
    int v0 = 0, v1 = 0, v2 = 0, v3 = 0;
    if (base + 3 < n) {
        int4 v = *(const int4*)(deg + base);
        v0 = v.x; v1 = v.y; v2 = v.z; v3 = v.w;
    } else {
        if (base + 0 < n) v0 = deg[base + 0];
        if (base + 1 < n) v1 = deg[base + 1];
        if (base + 2 < n) v2 = deg[base + 2];
        if (base + 3 < n) v3 = deg[base + 3];
    }
    int tot = v0 + v1 + v2 + v3;
    int incl = tot;
    for (int off = 1; off < 64; off <<= 1) {
        int t = __shfl_up(incl, off);
        if (lane >= off) incl += t;
    }
    if (lane == 63) wsum[wid] = incl;
    __syncthreads();
    int wave_prefix = 0;
    for (int w = 0; w < wid; ++w) wave_prefix += wsum[w];
    int block_prefix = 0;
    for (int w = 0; w < blockIdx.x; ++w) block_prefix += bsums[w];
    int excl = block_prefix + wave_prefix + (incl - tot);
    int e0 = excl, e1 = e0 + v0, e2 = e1 + v1, e3 = e2 + v2;
    if (base + 0 < n) { rowptr[base+0] = e0; cursor[base+0] = e0; dinv[base+0] = v0 > 0 ? rsqrtf((float)v0) : 0.0f; }
    if (base + 1 < n) { rowptr[base+1] = e1; cursor[base+1] = e1; dinv[base+1] = v1 > 0 ? rsqrtf((float)v1) : 0.0f; }
    if (base + 2 < n) { rowptr[base+2] = e2; cursor[base+2] = e2; dinv[base+2] = v2 > 0 ? rsqrtf((float)v2) : 0.0f; }
    if (base + 3 < n) { rowptr[base+3] = e3; cursor[base+3] = e3; dinv[base+3] = v3 > 0 ? rsqrtf((float)v3) : 0.0f; }
    if (blockIdx.x == 0 && tid == 0) {
        int t = 0;
        for (int w = 0; w < nb; ++w) t += bsums[w];
        rowptr[n] = t;
    }
}

// ---------------------------------------------------------------------------
// K3: scatter edges into CSR order (by dst); payload packed 8B = (src, adj)
__global__ void k_scatter(const int* __restrict__ src, const int* __restrict__ dst,
                          const float* __restrict__ dinv, int* __restrict__ cursor,
                          int2* __restrict__ edgep, int E,
                          const int* __restrict__ nnzCount) {
    GATE_ON_EMPTY(nnzCount);
    int stride = gridDim.x * blockDim.x;
    for (int e = blockIdx.x * blockDim.x + threadIdx.x; e < E; e += stride) {
        int d = dst[e], sN = src[e];
        int k = atomicAdd(&cursor[d], 1);
        float a = dinv[sN] * dinv[d];
        edgep[k] = make_int2(sN, __float_as_int(a));
    }
}

// ---------------------------------------------------------------------------
// K4: sparse_v = sign(w)*relu(|w|-sigmoid(s)); per-row flag; h0 written ONLY
//     for nonzero rows (zero rows of h0 are never read: all h0 consumers are
//     flag-guarded). Block-reduced nnz count -> 1 atomic per block.
__global__ void k_sparse_flag(const float* __restrict__ w, const float* __restrict__ s,
                              float* __restrict__ h0, int* __restrict__ rowNnz,
                              int* __restrict__ nnzCount, int N) {
    __shared__ int wred[4];
    int tid = threadIdx.x;
    int g = blockIdx.x * blockDim.x + tid;
    int node = g >> 4, l = g & 15;
    int nodeC = node < N ? node : N - 1;
    float t = 1.0f / (1.0f + expf(-s[0]));
    size_t off = (size_t)nodeC * 64 + l * 4;
    float4 v = *(const float4*)(w + off);
    float4 r;
    r.x = copysignf(fmaxf(fabsf(v.x) - t, 0.0f), v.x);
    r.y = copysignf(fmaxf(fabsf(v.y) - t, 0.0f), v.y);
    r.z = copysignf(fmaxf(fabsf(v.z) - t, 0.0f), v.z);
    r.w = copysignf(fmaxf(fabsf(v.w) - t, 0.0f), v.w);
    int nz = (r.x != 0.0f) | (r.y != 0.0f) | (r.z != 0.0f) | (r.w != 0.0f);
    for (int m = 1; m < 16; m <<= 1) nz |= __shfl_xor(nz, m);  // group-uniform
    if (node < N) {
        if (nz) *(float4*)(h0 + off) = r;   // uniform branch per group
        if (l == 0) rowNnz[node] = nz;
    }
    // block count of nonzero rows: one contribution per group
    int c = (node < N && l == 0) ? nz : 0;
    for (int m = 1; m < 64; m <<= 1) c += __shfl_xor(c, m);
    if ((tid & 63) == 0) wred[tid >> 6] = c;
    __syncthreads();
    if (tid == 0) {
        int tot = wred[0] + wred[1] + wred[2] + wred[3];
        if (tot) atomicAdd(nnzCount, tot);
    }
}

// ---------------------------------------------------------------------------
// K5: init sampled-row accumulator (flag-guarded h0 read) + reg-loss partial
//     (block-reduced, 1 atomic per block)
__global__ void k_samp_init(const float* __restrict__ h, const float* __restrict__ w,
                            const int* __restrict__ rowNnz,
                            const int* __restrict__ users, const int* __restrict__ pos,
                            const int* __restrict__ neg, float* __restrict__ samp,
                            float* __restrict__ partials, int B) {
    __shared__ float wred[4];
    int tid = threadIdx.x;
    int g = blockIdx.x * blockDim.x + tid;
    int j = g >> 4, l = g & 15;
    float ss = 0.0f;
    if (j < 3 * B) {
        int idx = (j < B) ? users[j] : ((j < 2 * B) ? pos[j - B] : neg[j - 2 * B]);
        float4 v = make_float4(0.f, 0.f, 0.f, 0.f);
        if (rowNnz[idx]) v = *(const float4*)(h + (size_t)idx * 64 + l * 4);
        *(float4*)(samp + (size_t)j * 64 + l * 4) = v;
        float4 e = *(const float4*)(w + (size_t)idx * 64 + l * 4);
        ss = e.x * e.x + e.y * e.y + e.z * e.z + e.w * e.w;
    }
    for (int m = 1; m < 64; m <<= 1) ss += __shfl_xor(ss, m);
    if ((tid & 63) == 0) wred[tid >> 6] = ss;
    __syncthreads();
    if (tid == 0) atomicAdd(&partials[0], wred[0] + wred[1] + wred[2] + wred[3]);
}

// K7: add h rows at sample indices (gated)
__global__ void k_samp_add(const float* __restrict__ h,
                           const int* __restrict__ users, const int* __restrict__ pos,
                           const int* __restrict__ neg, float* __restrict__ samp, int B,
                           const int* __restrict__ nnzCount) {
    GATE_ON_EMPTY(nnzCount);
    int g = blockIdx.x * blockDim.x + threadIdx.x;
    int j = g >> 4, l = g & 15;
    if (j >= 3 * B) return;
    int idx = (j < B) ? users[j] : ((j < 2 * B) ? pos[j - B] : neg[j - 2 * B]);
    float4 v = *(const float4*)(h + (size_t)idx * 64 + l * 4);
    float4 a = *(float4*)(samp + (size_t)j * 64 + l * 4);
    a.x += v.x; a.y += v.y; a.z += v.z; a.w += v.w;
    *(float4*)(samp + (size_t)j * 64 + l * 4) = a;
}

// ---------------------------------------------------------------------------
// K6: SpMM  hout[n] = sum_k adj_k * hin[src_k]; layer-0 variant skips
//     zero-flagged source rows (valid only when hin == sparse_v)
__global__ void k_spmm(const float* __restrict__ hin, float* __restrict__ hout,
                       const int* __restrict__ rowptr, const int2* __restrict__ edgep,
                       const int* __restrict__ rowNnz, int n,
                       const int* __restrict__ nnzCount) {
    GATE_ON_EMPTY(nnzCount);
    int g = blockIdx.x * blockDim.x + threadIdx.x;
    int node = g >> 4, l = g & 15;
    if (node >= n) return;
    int beg = rowptr[node], end = rowptr[node + 1];
    float4 acc = make_float4(0.f, 0.f, 0.f, 0.f);
    for (int k = beg; k < end; ++k) {
        int2 ep = edgep[k];
        int sN = ep.x;
        if (!rowNnz[sN]) continue;   // uniform across the 16-lane group
        float a = __int_as_float(ep.y);
        float4 v = *(const float4*)(hin + (size_t)sN * 64 + l * 4);
        acc.x = fmaf(a, v.x, acc.x);
        acc.y = fmaf(a, v.y, acc.y);
        acc.z = fmaf(a, v.z, acc.z);
        acc.w = fmaf(a, v.w, acc.w);
    }
    *(float4*)(hout + (size_t)node * 64 + l * 4) = acc;
}

__global__ void k_spmm_nf(const float* __restrict__ hin, float* __restrict__ hout,
                          const int* __restrict__ rowptr, const int2* __restrict__ edgep,
                          int n, const int* __restrict__ nnzCount) {
    GATE_ON_EMPTY(nnzCount);
    int g = blockIdx.x * blockDim.x + threadIdx.x;
    int node = g >> 4, l = g & 15;
    if (node >= n) return;
    int beg = rowptr[node], end = rowptr[node + 1];
    float4 acc = make_float4(0.f, 0.f, 0.f, 0.f);
    for (int k = beg; k < end; ++k) {
        int2 ep = edgep[k];
        int sN = ep.x;
        float a = __int_as_float(ep.y);
        float4 v = *(const float4*)(hin + (size_t)sN * 64 + l * 4);
        acc.x = fmaf(a, v.x, acc.x);
        acc.y = fmaf(a, v.y, acc.y);
        acc.z = fmaf(a, v.z, acc.z);
        acc.w = fmaf(a, v.w, acc.w);
    }
    *(float4*)(hout + (size_t)node * 64 + l * 4) = acc;
}

// ---------------------------------------------------------------------------
// K8: BPR scores (block-reduced, 1 atomic per block)
__global__ void k_scores(const float* __restrict__ samp, float* __restrict__ partials,
                         int B) {
    __shared__ float wred[4];
    int tid = threadIdx.x;
    int g = blockIdx.x * blockDim.x + tid;
    int j = g >> 4, l = g & 15;
    float sp = 0.0f;
    if (j < B) {
        float4 u = *(const float4*)(samp + (size_t)j * 64 + l * 4);
        float4 p = *(const float4*)(samp + (size_t)(j + B) * 64 + l * 4);
        float4 q = *(const float4*)(samp + (size_t)(j + 2 * B) * 64 + l * 4);
        float ps = u.x * p.x + u.y * p.y + u.z * p.z + u.w * p.w;
        float ns = u.x * q.x + u.y * q.y + u.z * q.z + u.w * q.w;
        for (int m = 1; m < 16; m <<= 1) {
            ps += __shfl_xor(ps, m);
            ns += __shfl_xor(ns, m);
        }
        if (l == 0) {
            float x = (ns - ps) * 0.0625f;  // all_emb = acc/4 -> score scale 1/16
            sp = fmaxf(x, 0.0f) + log1pf(expf(-fabsf(x)));  // stable softplus
        }
    }
    for (int m = 1; m < 64; m <<= 1) sp += __shfl_xor(sp, m);
    if ((tid & 63) == 0) wred[tid >> 6] = sp;
    __syncthreads();
    if (tid == 0) atomicAdd(&partials[1], wred[0] + wred[1] + wred[2] + wred[3]);
}

// ---------------------------------------------------------------------------
// K9: finalize the 4 scalar outputs
__global__ void k_final(const float* __restrict__ partials, const float* __restrict__ s,
                        float* __restrict__ out, int B) {
    float b = (float)B;
    float loss_emb = partials[1] / b;
    float reg_loss = 0.5f * partials[0] / b * 1e-4f;
    float s0 = s[0];
    float s_loss = 0.5f * s0 * s0 / b * 1e-4f;
    out[0] = loss_emb + reg_loss + s_loss;
    out[1] = loss_emb;
    out[2] = reg_loss;
    out[3] = s_loss;
}

// ---------------------------------------------------------------------------
extern "C" void kernel_launch(void* const* d_in, const int* in_sizes, int n_in,
                              void* d_out, int out_size, void* d_ws, size_t ws_size,
                              hipStream_t stream) {
    const float* weight = (const float*)d_in[0];
    const float* s      = (const float*)d_in[1];
    const int*   src    = (const int*)d_in[2];
    const int*   dst    = (const int*)d_in[3];
    const int*   users  = (const int*)d_in[4];
    const int*   pos    = (const int*)d_in[5];
    const int*   neg    = (const int*)d_in[6];

    const int D = 64;
    const int N = in_sizes[0] / D;
    const int E = in_sizes[2];
    const int B = in_sizes[4];
    const int NB = CDIV(N, 4096);   // must be <= 64 (N <= 262144)

    char* wp = (char*)d_ws;
    auto alloc = [&](size_t bytes) -> void* {
        void* p = (void*)wp;
        wp += (bytes + 255) & ~(size_t)255;
        return p;
    };
    int*   deg      = (int*)alloc((size_t)N * 4);
    float* dinv     = (float*)alloc((size_t)N * 4);
    int*   rowptr   = (int*)alloc((size_t)(N + 1) * 4);
    int*   cursor   = (int*)alloc((size_t)N * 4);
    int*   rowNnz   = (int*)alloc((size_t)N * 4);
    int*   blockSums= (int*)alloc((size_t)1024 * 4);
    int2*  edgep    = (int2*)alloc((size_t)E * 8);
    float* h0       = (float*)alloc((size_t)N * D * 4);
    float* h1       = (float*)alloc((size_t)N * D * 4);
    float* samp     = (float*)alloc((size_t)3 * B * D * 4);
    float* partials = (float*)alloc(256);
    int*   nnzCount = (int*)(partials + 8);

    hipMemsetAsync(deg, 0, (size_t)N * 4, stream);
    hipMemsetAsync(partials, 0, 64, stream);  // partials[0..1] + nnzCount

    k_sparse_flag<<<CDIV(N * 16, 256), 256, 0, stream>>>(weight, s, h0, rowNnz,
                                                         nnzCount, N);
    k_hist<<<2048, 256, 0, stream>>>(dst, deg, E, nnzCount);
    k_scan_reduce<<<NB, 1024, 0, stream>>>(deg, blockSums, N, nnzCount);
    k_scan_final<<<NB, 1024, 0, stream>>>(deg, blockSums, rowptr, cursor, dinv, N, NB,
                                          nnzCount);
    k_scatter<<<2048, 256, 0, stream>>>(src, dst, dinv, cursor, edgep, E, nnzCount);
    k_samp_init<<<CDIV(3 * B * 16, 256), 256, 0, stream>>>(h0, weight, rowNnz, users,
                                                           pos, neg, samp, partials, B);
    // layer 0: per-edge zero-row skip via rowNnz (valid only for sparse_v input)
    k_spmm<<<CDIV(N * 16, 256), 256, 0, stream>>>(h0, h1, rowptr, edgep, rowNnz, N,
                                                  nnzCount);
    k_samp_add<<<CDIV(3 * B * 16, 256), 256, 0, stream>>>(h1, users, pos, neg, samp, B,
                                                          nnzCount);
    k_spmm_nf<<<CDIV(N * 16, 256), 256, 0, stream>>>(h1, h0, rowptr, edgep, N, nnzCount);
    k_samp_add<<<CDIV(3 * B * 16, 256), 256, 0, stream>>>(h0, users, pos, neg, samp, B,
                                                          nnzCount);
    k_spmm_nf<<<CDIV(N * 16, 256), 256, 0, stream>>>(h0, h1, rowptr, edgep, N, nnzCount);
    k_samp_add<<<CDIV(3 * B * 16, 256), 256, 0, stream>>>(h1, users, pos, neg, samp, B,
                                                          nnzCount);
    k_scores<<<CDIV(B * 16, 256), 256, 0, stream>>>(samp, partials, B);
    k_final<<<1, 1, 0, stream>>>(partials, s, (float*)d_out, B);
}